// Round 9
// baseline (315.201 us; speedup 1.0000x reference)
//
#include <hip/hip_runtime.h>
#include <hip/hip_bf16.h>

#define H 2048
#define K 1024
#define R 3
#define BB 8
#define S 2048

typedef __bf16 bf16x8 __attribute__((ext_vector_type(8)));
typedef float f32x4 __attribute__((ext_vector_type(4)));
typedef unsigned short ushort8 __attribute__((ext_vector_type(8)));

static __device__ __forceinline__ unsigned short f2bf(float f) {
    unsigned int u = __float_as_uint(f);
    u += 0x7FFFu + ((u >> 16) & 1u);   // round-to-nearest-even
    return (unsigned short)(u >> 16);
}

#define GLOAD_LDS16(g, l)                                                      \
    __builtin_amdgcn_global_load_lds(                                          \
        (const __attribute__((address_space(1))) void*)(g),                    \
        (__attribute__((address_space(3))) void*)(l), 16, 0, 0)

// ---------------- convert hidden f32 -> bf16 ----------------
__global__ __launch_bounds__(256) void cvt_hs(const float* __restrict__ in,
                                              unsigned short* __restrict__ out,
                                              int n8) {
    int stride = gridDim.x * blockDim.x;
    for (int i = blockIdx.x * blockDim.x + threadIdx.x; i < n8; i += stride) {
        const float4* p = (const float4*)(in + (size_t)i * 8);
        float4 a = p[0], b = p[1];
        union { unsigned short us[8]; ushort8 v; } o;
        o.us[0] = f2bf(a.x); o.us[1] = f2bf(a.y);
        o.us[2] = f2bf(a.z); o.us[3] = f2bf(a.w);
        o.us[4] = f2bf(b.x); o.us[5] = f2bf(b.y);
        o.us[6] = f2bf(b.z); o.us[7] = f2bf(b.w);
        *(ushort8*)(out + (size_t)i * 8) = o.v;
    }
}

// -------- transpose+convert: in f32 [rows][cols] -> out bf16 [cols][rows] ----
__global__ __launch_bounds__(256) void tpose(const float* __restrict__ in,
                                             unsigned short* __restrict__ out,
                                             int rows, int cols) {
    __shared__ float tile[32][33];
    int rr = blockIdx.z;
    const float* ip = in + (size_t)rr * rows * cols;
    unsigned short* op = out + (size_t)rr * rows * cols;
    int x = blockIdx.x * 32 + threadIdx.x;
    int y0 = blockIdx.y * 32 + threadIdx.y;
#pragma unroll
    for (int j = 0; j < 32; j += 8)
        tile[threadIdx.y + j][threadIdx.x] = ip[(size_t)(y0 + j) * cols + x];
    __syncthreads();
    int ox = blockIdx.y * 32 + threadIdx.x;
    int oy0 = blockIdx.x * 32 + threadIdx.y;
#pragma unroll
    for (int j = 0; j < 32; j += 8)
        op[(size_t)(oy0 + j) * rows + ox] = f2bf(tile[threadIdx.x][threadIdx.y + j]);
}

// ==== 256x256 8-phase NT GEMM, BK=64, dbuf-2, REGISTER READ-AHEAD ====
// Key schedule property: ds_reads issued in phase p feed phase p+1's MFMA.
// The compiler then auto-emits COUNTED lgkmcnt before each MFMA (waits only
// for prior-phase reads, already drained) -> LDS pipe of phase p overlaps
// MFMA of phase p. Fragment regs double-buffered: aA/aB (A-lo/A-hi),
// bL/bH (B-lo/B-hi). Quadrants per K-tile: Q1=(i0-3,j0-1)=aAxbL,
// Q2=(i0-3,j2-3)=aAxbH, Q3=(i4-7,j0-1)=aBxbL, Q4=(i4-7,j2-3)=aBxbH.
// Read plan (iter t: tiles t@s0, t+1@s1):
//   pro: A-lo(0),B-lo(0)   P1: B-hi(t)    P2: A-hi(t)    P3: -
//   P4: A-lo(t+1),B-lo(t+1)  P5: B-hi(t+1)  P6: A-hi(t+1)  P7: -
//   P8: A-lo(t+2),B-lo(t+2) [pf]
// Stage plan: P1/P2: A(t+1)->s1; P3/P4: B(t+2)->s0; P5/P6: A(t+2)->s0;
//   P7/P8: B(t+3)->s1.
// Gates: end-P3 vmcnt(2) [10 out; forces B(t+1)+A(t+1), leaves B(t+2)h0];
//   end-P7 vmcnt(2) [10 out; forces B(t+2)+A(t+2), leaves B(t+3)h0]. Cross-
//   tile reads at P4/P8 occur AFTER gate+barrier -> staged data visible.
// WAR: reads issued at phase p complete before the wave's p+1 MFMA wait,
//   hence before barrier p+1; all stage targets overwritten >=2 barriers
//   after their last readers' drain point (audited per region).
// EPI 0: out = bf16 gelu(acc+bias) -> h
// EPI 1: out = bf16 (acc+bias+resid_bf16) IN PLACE over resid; row stats->Part
template <int KC, int EPI>
__global__ __launch_bounds__(512, 2) void gemm_8ph(
    const unsigned short* __restrict__ A, const unsigned short* __restrict__ Bt,
    const int* __restrict__ role, const float* __restrict__ bias,
    const unsigned short* __restrict__ resid, void* __restrict__ Out,
    float2* __restrict__ Part, int N) {
    constexpr int NT = KC / 64;          // even
    __shared__ char smem[131072];
    const int tid = threadIdx.x;
    const int wid = tid >> 6, lane = tid & 63;
    const int wm = wid >> 2, wn = wid & 3;
    const int lr = lane & 15, lc = lane >> 4;

    const int nx = N >> 8;
    const int cpx = gridDim.x >> 3;
    const int orig = (blockIdx.x & 7) * cpx + (blockIdx.x >> 3);
    const int tn = orig % nx;
    const int tmz = orig / nx;
    const int tm = tmz & 7;              // S/256 = 8 m-tiles
    const int z = tmz >> 3;
    const int r = role[z];

    const char* Ab = (const char*)(A + ((size_t)z * S + (size_t)tm * 256) * KC);
    const char* Bb = (const char*)(Bt + ((size_t)r * N + (size_t)tn * 256) * KC);

    const int P16 = tid * 16;

#define STAGE16(gbase, ldsoff, kt, half)                                       \
    do {                                                                       \
        _Pragma("unroll") for (int c_ = 0; c_ < 2; c_++) {                     \
            int P_ = c_ * 8192 + P16;                                          \
            int L_ = P_ ^ (((P_ >> 7) & 7) << 4);                              \
            const char* g_ = (gbase) +                                         \
                (size_t)((half) * 128 + (L_ >> 7)) * (KC * 2) +                \
                (size_t)(kt) * 128 + (L_ & 127);                               \
            GLOAD_LDS16(g_, smem + (ldsoff) + (half) * 16384 + P_);            \
        }                                                                      \
    } while (0)

    // prologue: A(0)->s0, B(0)->s0, B(1)->s1; force A(0),B(0); B(1) flying
    STAGE16(Ab, 0, 0, 0);        STAGE16(Ab, 0, 0, 1);
    STAGE16(Bb, 32768, 0, 0);    STAGE16(Bb, 32768, 0, 1);
    STAGE16(Bb, 98304, 1, 0);    STAGE16(Bb, 98304, 1, 1);
    asm volatile("s_waitcnt vmcnt(4)" ::: "memory");
    asm volatile("s_barrier" ::: "memory");

    f32x4 acc[8][4] = {};
    const int swz = (lr & 7) << 4;
    const int ck0 = (lc << 4) ^ swz;
    const int ck1 = ck0 ^ 0x40;
    const char* sm = smem;

    bf16x8 aA[4][2], aB[4][2], bL[2][2], bH[2][2];

#define RDA(dst, ibase, SL)                                                    \
    _Pragma("unroll") for (int i_ = 0; i_ < 4; i_++) {                         \
        int rb_ = (wm * 128 + ((ibase) + i_) * 16 + lr) << 7;                  \
        dst[i_][0] = *(const bf16x8*)(sm + (SL) + rb_ + ck0);                  \
        dst[i_][1] = *(const bf16x8*)(sm + (SL) + rb_ + ck1); }
#define RDB(dst, jbase, SL)                                                    \
    _Pragma("unroll") for (int j_ = 0; j_ < 2; j_++) {                         \
        int rb_ = (wn * 64 + ((jbase) + j_) * 16 + lr) << 7;                   \
        dst[j_][0] = *(const bf16x8*)(sm + (SL) + 32768 + rb_ + ck0);          \
        dst[j_][1] = *(const bf16x8*)(sm + (SL) + 32768 + rb_ + ck1); }
#define QMFMA(ar, br, IOFF, JOFF)                                              \
    _Pragma("unroll") for (int kk = 0; kk < 2; kk++)                           \
    _Pragma("unroll") for (int i_ = 0; i_ < 4; i_++)                           \
    _Pragma("unroll") for (int j_ = 0; j_ < 2; j_++)                           \
        acc[(IOFF) + i_][(JOFF) + j_] = __builtin_amdgcn_mfma_f32_16x16x32_bf16( \
            ar[i_][kk], br[j_][kk], acc[(IOFF) + i_][(JOFF) + j_], 0, 0, 0);
#define BAR() asm volatile("s_barrier" ::: "memory")

    // pre-loop: fragments for Q1(0)
    RDA(aA, 0, 0);
    RDB(bL, 0, 0);

#pragma unroll 1
    for (int t = 0; t < NT; t += 2) {
        const bool pf = (t + 2) < NT;
        // ---- P1: read B-hi(t); stage A(t+1)h0->s1; MFMA Q1(t) ----
        RDB(bH, 2, 0);
        STAGE16(Ab, 65536, t + 1, 0);
        __builtin_amdgcn_s_setprio(1); QMFMA(aA, bL, 0, 0);
        __builtin_amdgcn_s_setprio(0); BAR();
        // ---- P2: read A-hi(t); stage A(t+1)h1->s1; MFMA Q2(t) ----
        RDA(aB, 4, 0);
        STAGE16(Ab, 65536, t + 1, 1);
        __builtin_amdgcn_s_setprio(1); QMFMA(aA, bH, 0, 2);
        __builtin_amdgcn_s_setprio(0); BAR();
        // ---- P3: stage B(t+2)h0->s0; MFMA Q3(t); gate ----
        if (pf) STAGE16(Bb, 32768, t + 2, 0);
        __builtin_amdgcn_s_setprio(1); QMFMA(aB, bL, 4, 0);
        __builtin_amdgcn_s_setprio(0);
        if (pf) asm volatile("s_waitcnt vmcnt(2)" ::: "memory");
        else    asm volatile("s_waitcnt vmcnt(0)" ::: "memory");
        BAR();
        // ---- P4: read A-lo(t+1),B-lo(t+1)@s1; stage B(t+2)h1->s0; MFMA Q4(t) ----
        RDA(aA, 0, 65536);
        RDB(bL, 0, 65536);
        if (pf) STAGE16(Bb, 32768, t + 2, 1);
        __builtin_amdgcn_s_setprio(1); QMFMA(aB, bH, 4, 2);
        __builtin_amdgcn_s_setprio(0); BAR();
        // ---- P5: read B-hi(t+1); stage A(t+2)h0->s0; MFMA Q1(t+1) ----
        RDB(bH, 2, 65536);
        if (pf) STAGE16(Ab, 0, t + 2, 0);
        __builtin_amdgcn_s_setprio(1); QMFMA(aA, bL, 0, 0);
        __builtin_amdgcn_s_setprio(0); BAR();
        // ---- P6: read A-hi(t+1); stage A(t+2)h1->s0; MFMA Q2(t+1) ----
        RDA(aB, 4, 65536);
        if (pf) STAGE16(Ab, 0, t + 2, 1);
        __builtin_amdgcn_s_setprio(1); QMFMA(aA, bH, 0, 2);
        __builtin_amdgcn_s_setprio(0); BAR();
        // ---- P7: stage B(t+3)h0->s1; MFMA Q3(t+1); gate ----
        if (pf) STAGE16(Bb, 98304, t + 3, 0);
        __builtin_amdgcn_s_setprio(1); QMFMA(aB, bL, 4, 0);
        __builtin_amdgcn_s_setprio(0);
        if (pf) asm volatile("s_waitcnt vmcnt(2)" ::: "memory");
        BAR();
        // ---- P8: read A-lo(t+2),B-lo(t+2)@s0 [pf]; stage B(t+3)h1->s1; MFMA Q4(t+1) ----
        if (pf) { RDA(aA, 0, 0); RDB(bL, 0, 0); }
        if (pf) STAGE16(Bb, 98304, t + 3, 1);
        __builtin_amdgcn_s_setprio(1); QMFMA(aB, bH, 4, 2);
        __builtin_amdgcn_s_setprio(0);
        if (pf) BAR();
    }
#undef STAGE16
#undef RDA
#undef RDB
#undef QMFMA
#undef BAR

    // ---- epilogue ----
    const int base_m = tm * 256 + wm * 128;
    const int base_n = tn * 256 + wn * 64;
    float bn[4];
    const float* bp = bias + (size_t)r * N + base_n;
#pragma unroll
    for (int j = 0; j < 4; j++) bn[j] = bp[j * 16 + lr];

    if (EPI == 0) {
        unsigned short* o = (unsigned short*)Out;
#pragma unroll
        for (int i = 0; i < 8; i++) {
#pragma unroll
            for (int j = 0; j < 4; j++) {
#pragma unroll
                for (int q = 0; q < 4; q++) {
                    size_t grow = (size_t)z * S + base_m + i * 16 + lc * 4 + q;
                    int col = base_n + j * 16 + lr;
                    float x = acc[i][j][q] + bn[j];
                    float g = 0.5f * x * (1.0f + erff(x * 0.70710678118654752f));
                    o[grow * N + col] = f2bf(g);
                }
            }
        }
    } else {
        unsigned short* o = (unsigned short*)Out;     // y bf16 (in place on resid)
        float* pl = (float*)smem;                     // [8][256] partials
        __syncthreads();
#pragma unroll
        for (int i = 0; i < 8; i++) {
#pragma unroll
            for (int q = 0; q < 4; q++) {
                size_t grow = (size_t)z * S + base_m + i * 16 + lc * 4 + q;
                float s = 0.f, sq = 0.f;
#pragma unroll
                for (int j = 0; j < 4; j++) {
                    int col = base_n + j * 16 + lr;
                    float rv = __uint_as_float(((unsigned)resid[grow * (size_t)N + col]) << 16);
                    float y = acc[i][j][q] + bn[j] + rv;
                    o[grow * (size_t)N + col] = f2bf(y);
                    s += y; sq += y * y;
                }
#pragma unroll
                for (int off = 1; off < 16; off <<= 1) {
                    s  += __shfl_xor(s, off);
                    sq += __shfl_xor(sq, off);
                }
                if (lr == 0) {
                    int rloc = wm * 128 + i * 16 + lc * 4 + q;
                    pl[wn * 256 + rloc] = s;
                    pl[(4 + wn) * 256 + rloc] = sq;
                }
            }
        }
        __syncthreads();
        if (tid < 256) {
            float s  = pl[tid] + pl[256 + tid] + pl[512 + tid] + pl[768 + tid];
            float sq = pl[1024 + tid] + pl[1280 + tid] + pl[1536 + tid] + pl[1792 + tid];
            size_t grow = (size_t)z * S + tm * 256 + tid;
            Part[(size_t)tn * (BB * S) + grow] = make_float2(s, sq);
        }
    }
}

// ------- LayerNorm: partials + y(bf16) -> out(f32), one block per row -------
__global__ __launch_bounds__(256) void ln2(const unsigned short* __restrict__ ybf,
                                           const float2* __restrict__ part,
                                           const int* __restrict__ role,
                                           const float* __restrict__ gamma,
                                           const float* __restrict__ beta,
                                           float* __restrict__ out) {
    int row = blockIdx.x;
    int z = row >> 11;                 // row / S
    int r = role[z];
    float s = 0.f, ss = 0.f;
#pragma unroll
    for (int nb = 0; nb < 8; nb++) {
        float2 p = part[(size_t)nb * (BB * S) + row];
        s += p.x; ss += p.y;
    }
    float mean = s * (1.0f / H);
    float var = ss * (1.0f / H) - mean * mean;
    float rstd = rsqrtf(var + 1e-5f);
    int t = threadIdx.x;
    ushort8 yv = ((const ushort8*)(ybf + (size_t)row * H))[t];
    const float4* gp = (const float4*)(gamma + (size_t)r * H);
    const float4* bp = (const float4*)(beta + (size_t)r * H);
    float4 g0 = gp[2 * t], g1 = gp[2 * t + 1];
    float4 b0 = bp[2 * t], b1 = bp[2 * t + 1];
    float yo[8];
#pragma unroll
    for (int e = 0; e < 8; e++)
        yo[e] = (__uint_as_float(((unsigned)yv[e]) << 16) - mean) * rstd;
    float4 r0, r1;
    r0.x = yo[0] * g0.x + b0.x; r0.y = yo[1] * g0.y + b0.y;
    r0.z = yo[2] * g0.z + b0.z; r0.w = yo[3] * g0.w + b0.w;
    r1.x = yo[4] * g1.x + b1.x; r1.y = yo[5] * g1.y + b1.y;
    r1.z = yo[6] * g1.z + b1.z; r1.w = yo[7] * g1.w + b1.w;
    float4* op = (float4*)(out + (size_t)row * H);
    op[2 * t] = r0;
    op[2 * t + 1] = r1;
}

extern "C" void kernel_launch(void* const* d_in, const int* in_sizes, int n_in,
                              void* d_out, int out_size, void* d_ws, size_t ws_size,
                              hipStream_t stream) {
    const int* role = (const int*)d_in[0];
    const float* hs = (const float*)d_in[1];
    const float* Wd = (const float*)d_in[2];
    const float* bd = (const float*)d_in[3];
    const float* Wu = (const float*)d_in[4];
    const float* bu = (const float*)d_in[5];
    const float* gamma = (const float*)d_in[6];
    const float* beta = (const float*)d_in[7];
    float* out = (float*)d_out;

    char* ws = (char*)d_ws;
    // region A (64 MiB @0): hs_bf (cvt -> G1, resid of G2), then y_bf (G2 -> LN, in place)
    unsigned short* hs_bf = (unsigned short*)ws;
    unsigned short* y_bf = (unsigned short*)ws;
    // region B (12 MiB @64Mi): wd_t (tpose -> G1), then partials (G2 -> LN)
    unsigned short* wd_t = (unsigned short*)(ws + 67108864);
    float2* part = (float2*)(ws + 67108864);
    // region C (12 MiB @76Mi): wu_t
    unsigned short* wu_t = (unsigned short*)(ws + 67108864 + 12582912);
    // region D (32 MiB @88Mi): h
    unsigned short* h_ws = (unsigned short*)(ws + 67108864 + 2 * 12582912);

    cvt_hs<<<4096, 256, 0, stream>>>(hs, hs_bf, (BB * S * H) / 8);
    dim3 tb(32, 8);
    tpose<<<dim3(K / 32, H / 32, R), tb, 0, stream>>>(Wd, wd_t, H, K);
    tpose<<<dim3(H / 32, K / 32, R), tb, 0, stream>>>(Wu, wu_t, K, H);
    // GEMM1: h = gelu(hs_bf x Wd^T + bd), bf16; 256 blocks
    gemm_8ph<H, 0><<<(K / 256) * 8 * BB, 512, 0, stream>>>(hs_bf, wd_t, role, bd,
                                                           nullptr, h_ws, nullptr, K);
    // GEMM2: y = h x Wu^T + bu + hs_bf, bf16 in place + partial stats; 512 blocks
    gemm_8ph<K, 1><<<(H / 256) * 8 * BB, 512, 0, stream>>>(h_ws, wu_t, role, bu,
                                                           hs_bf, y_bf, part, H);
    ln2<<<BB * S, 256, 0, stream>>>(y_bf, part, role, gamma, beta, out);
}